// Round 5
// baseline (305.849 us; speedup 1.0000x reference)
//
#include <hip/hip_runtime.h>

// Problem constants (from reference setup_inputs)
#define LATDIM 128
#define ANUM   64
#define NNODES 10000
#define PERIOD 625     // period of (64*i mod 10000); gcd(64,10000)=16
#define NPBLK  8       // P-producer blocks (8 anchors each)
#define NTBLK  157     // T2b-producer blocks (4 s each; 157*4=628>=625)
#define NPREP  (NPBLK + NTBLK)          // 165
#define NMAIN  313                      // 10000 / 32 n per block
#define MAGIC  0x1F2E3D4Cu             // != 0xAAAAAAAA poison
#define WP4    33                       // W_s row stride in float4 (132 floats)

// ---------------------------------------------------------------------------
// Verified algebra (r3/r4 passed, absmax 9.8e-4):
//   out[n,o] = (1/A)*sum_a dists[a,n]*P[a,o] + T2b[n%625,o]
//   P[a,o]   = sum_k E[anchor[a],k]*W[o,k]
//   T2b[s,o] = b[o] + (1/A)*sum_k S[s,k]*W[o,128+k],  S[s,k]=sum_a E[(64s+a)%N,k]
//
// r4->r5: single fused kernel. Prep blocks (0..164) produce P/T2b and
// release per-block flags (threadfence+syncthreads+agent release store).
// Main blocks (165..477) stage their dists tile into LDS DURING the spin
// wait, hold P in 64 VGPRs (no LDS hot path), and wait on T2 flags only at
// the epilogue. Deadlock-safe by capacity: 71.7KB LDS -> 2 blocks/CU ->
// 512 slots >= 478 blocks, 8 waves/CU, VGPR << 256/wave => full grid
// co-resident. Spin has an iteration cap so a model error fails loudly
// (wrong answer) instead of hanging the harness.
// ---------------------------------------------------------------------------

__global__ __launch_bounds__(256) void fused_kernel(
    const float* __restrict__ embeds,   // [N, d] fp32
    const float* __restrict__ dists,    // [A, N] fp32
    const float* __restrict__ W,        // [d, 2d] fp32 row-major
    const float* __restrict__ b,        // [d] fp32
    const int*   __restrict__ anchor,   // [A] int32
    float* __restrict__ P,              // [A, d]    ws
    float* __restrict__ T2b,            // [625, d]  ws
    unsigned int* __restrict__ flags,   // [256]     ws (poisoned 0xAA..)
    float* __restrict__ out)            // [N, d] fp32
{
    __shared__ float lds[128 * 4 * WP4 + 8 * LATDIM];   // 71,680 B
    const int tid = threadIdx.x;
    const int bid = blockIdx.x;

    if (bid < NPREP) {
        // ===================== producer blocks =====================
        float*  W_s  = lds;                       // [128][132]
        float*  X_s  = lds + 128 * 4 * WP4;       // [8][128]
        float4* W_s4 = (float4*)W_s;
        const float4* X_s4 = (const float4*)X_s;
        const bool isP = (bid < NPBLK);
        const int  off = isP ? 0 : LATDIM;
        const int  col = tid & 127, g = tid >> 7;   // g in {0,1}

        // Stage W half -> LDS (4096 float4, coalesced; pad 33 -> phase-2
        // b128 reads hit 8 distinct addrs/bank = the 1KB/8cyc floor).
        #pragma unroll
        for (int it = 0; it < 16; ++it) {
            int f = it * 256 + tid;          // 0..4095
            int r = f >> 5, c4 = f & 31;
            W_s4[r * WP4 + c4] =
                *(const float4*)(W + r * (2 * LATDIM) + off + 4 * c4);
        }

        if (isP) {
            const int a0 = bid * NPBLK;
            #pragma unroll
            for (int j2 = 0; j2 < 4; ++j2) {
                int j = g * 4 + j2;
                X_s[j * LATDIM + col] =
                    embeds[(size_t)anchor[a0 + j] * LATDIM + col];
            }
            __syncthreads();
            if (tid < 128) {
                float acc[8] = {};
                #pragma unroll 8
                for (int k4 = 0; k4 < 32; ++k4) {
                    float4 w = W_s4[tid * WP4 + k4];
                    #pragma unroll
                    for (int j = 0; j < 8; ++j) {
                        float4 e = X_s4[j * 32 + k4];
                        acc[j] += e.x*w.x + e.y*w.y + e.z*w.z + e.w*w.w;
                    }
                }
                #pragma unroll
                for (int j = 0; j < 8; ++j)
                    P[(size_t)(a0 + j) * LATDIM + tid] = acc[j];
            }
        } else {
            const int s0 = (bid - NPBLK) * 4;
            // Phase 1: 4 disjoint 64-row windows, rows split across g.
            float acc[4] = {};
            #pragma unroll
            for (int j = 0; j < 4; ++j) {
                int base = ((s0 + j) * ANUM) % NNODES;
                #pragma unroll 8
                for (int r = g; r < ANUM; r += 2) {
                    int row = base + r;
                    if (row >= NNODES) row -= NNODES;
                    acc[j] += embeds[(size_t)row * LATDIM + col];
                }
            }
            #pragma unroll
            for (int j = 0; j < 4; ++j)
                X_s[(g * 4 + j) * LATDIM + col] = acc[j];
            __syncthreads();
            if (tid < 128) {
                float accO[4] = {};
                #pragma unroll 8
                for (int k4 = 0; k4 < 32; ++k4) {
                    float4 w = W_s4[tid * WP4 + k4];
                    #pragma unroll
                    for (int j = 0; j < 4; ++j) {
                        float4 sa = X_s4[j * 32 + k4];
                        float4 sb = X_s4[(4 + j) * 32 + k4];
                        accO[j] += (sa.x+sb.x)*w.x + (sa.y+sb.y)*w.y
                                 + (sa.z+sb.z)*w.z + (sa.w+sb.w)*w.w;
                    }
                }
                const float bias = b[tid];
                #pragma unroll
                for (int j = 0; j < 4; ++j) {
                    int s = s0 + j;
                    if (s < PERIOD)
                        T2b[(size_t)s * LATDIM + tid] =
                            bias + accO[j] * (1.0f / ANUM);
                }
            }
        }
        // Release: make this block's global stores visible, then flag.
        __threadfence();
        __syncthreads();
        if (tid == 0)
            __hip_atomic_store(&flags[bid], MAGIC, __ATOMIC_RELEASE,
                               __HIP_MEMORY_SCOPE_AGENT);
    } else {
        // ===================== consumer (main) blocks =====================
        const int m   = bid - NPREP;
        const int nb0 = m * 32;
        float* D_s = lds;                        // [64][32] floats (8 KB)

        // Stage dists tile while producers run (overlaps the spin wait).
        #pragma unroll
        for (int it = 0; it < 2; ++it) {
            int idx = it * 256 + tid;            // 0..511
            int row = idx >> 3, c4 = idx & 7;
            int colg = nb0 + 4 * c4;
            if (colg + 3 >= NNODES) colg = NNODES - 4;   // clamp (garbage ok)
            ((float4*)D_s)[row * 8 + c4] =
                *(const float4*)(dists + (size_t)row * NNODES + colg);
        }

        // Wait for P (slots 0..7). syncthreads_and also publishes D_s.
        for (int it = 0; it < (1 << 22); ++it) {
            int ok = 1;
            if (tid < NPBLK)
                ok = (__hip_atomic_load(&flags[tid], __ATOMIC_ACQUIRE,
                                        __HIP_MEMORY_SCOPE_AGENT) == MAGIC);
            if (__syncthreads_and(ok)) break;
            __builtin_amdgcn_s_sleep(2);
        }
        __threadfence();   // acquire for all threads' subsequent P reads

        const int lane = tid & 63;
        const int wv   = __builtin_amdgcn_readfirstlane(tid >> 6); // 0..3
        const int o    = (wv & 1) * 64 + lane;
        const int nc   = wv >> 1;
        const int nb   = nb0 + nc * 16;
        const bool live = (nb + 16) <= NNODES;   // last block, chunk 1: dead

        float p[64];
        #pragma unroll
        for (int a = 0; a < ANUM; ++a)
            p[a] = P[a * LATDIM + o];            // coalesced, L2/LLC

        float acc[16] = {};
        const float4* D4 = (const float4*)D_s;
        #pragma unroll
        for (int a = 0; a < ANUM; ++a) {
            #pragma unroll
            for (int j4 = 0; j4 < 4; ++j4) {
                float4 d = D4[a * 8 + nc * 4 + j4];   // wave-broadcast LDS
                acc[j4 * 4 + 0] += d.x * p[a];
                acc[j4 * 4 + 1] += d.y * p[a];
                acc[j4 * 4 + 2] += d.z * p[a];
                acc[j4 * 4 + 3] += d.w * p[a];
            }
        }

        // Wait for T2b (slots 8..164) — usually already done by now.
        for (int it = 0; it < (1 << 22); ++it) {
            int ok = 1;
            if (tid < NTBLK)
                ok = (__hip_atomic_load(&flags[NPBLK + tid], __ATOMIC_ACQUIRE,
                                        __HIP_MEMORY_SCOPE_AGENT) == MAGIC);
            if (__syncthreads_and(ok)) break;
            __builtin_amdgcn_s_sleep(2);
        }
        __threadfence();

        if (live) {
            #pragma unroll
            for (int j = 0; j < 16; ++j) {
                int n = nb + j;
                int s = n % PERIOD;
                out[(size_t)n * LATDIM + o] =
                    acc[j] * (1.0f / ANUM) + T2b[(size_t)s * LATDIM + o];
            }
        }
    }
}

extern "C" void kernel_launch(void* const* d_in, const int* in_sizes, int n_in,
                              void* d_out, int out_size, void* d_ws, size_t ws_size,
                              hipStream_t stream) {
    const float* embeds = (const float*)d_in[0];   // [10000,128]
    const float* dists  = (const float*)d_in[1];   // [64,10000]
    const float* W      = (const float*)d_in[2];   // [128,256]
    const float* b      = (const float*)d_in[3];   // [128]
    const int*   anchor = (const int*)d_in[4];     // [64]
    float* out = (float*)d_out;                    // [10000,128]

    float* P   = (float*)d_ws;                     // 8192 floats
    float* T2b = P + ANUM * LATDIM;                // 80000 floats
    unsigned int* flags = (unsigned int*)(T2b + PERIOD * LATDIM);
    // ws used: 352,768 B + 1 KB flags (poisoned 0xAAAAAAAA != MAGIC each run)

    fused_kernel<<<NPREP + NMAIN, 256, 0, stream>>>(
        embeds, dists, W, b, anchor, P, T2b, flags, out);
}

// Round 6
// 83.860 us; speedup vs baseline: 3.6471x; 3.6471x over previous
//
#include <hip/hip_runtime.h>

// Problem constants (from reference setup_inputs)
#define LATDIM 128     // d
#define ANUM   64      // anchor sets A
#define NNODES 10000   // N
#define PERIOD 625     // period of (64*i mod 10000); gcd(64,10000)=16
#define TN     32      // n per main block
#define PPB    8       // anchors per P-block
#define SPB    4       // s-values per T2-block
#define PBLK   (ANUM / PPB)                 // 8 blocks
#define TBLK   ((PERIOD + SPB - 1) / SPB)   // 157 blocks
#define WP4    33      // W_s row stride in float4 units (132 floats)

// ---------------------------------------------------------------------------
// Verified algebra (r3/r4/r5 all passed, absmax 9.8e-4):
//   out[n,o] = (1/A)*sum_a dists[a,n]*P[a,o] + T2b[n%625,o]
//   P[a,o]   = sum_k E[anchor[a],k]*W[o,k]
//   T2b[s,o] = b[o] + (1/A)*sum_k S[s,k]*W[o,128+k], S[s,k]=sum_a E[(64s+a)%N,k]
//
// r5 lesson (248us fused kernel): p[64]-in-VGPR + dual-path kernel -> 256
// VGPRs -> scratch spills (FETCH 106MB / WRITE 190MB of self-inflicted
// traffic); agent-scope flag polling added coherent line-fetch storms.
// REVERTED to the r4 two-kernel structure (84.2us measured).
// r6 delta vs r4: prep widened to 256 threads — phase-2 k-range split
// across thread-halves with an LDS partial reduce, phase-1 rows split
// likewise. Main kernel is r4's byte-identical measured-good version.
// ---------------------------------------------------------------------------

__global__ __launch_bounds__(256) void prep_kernel(
    const float* __restrict__ embeds,   // [N, d] fp32
    const float* __restrict__ W,        // [d, 2d] fp32 row-major
    const float* __restrict__ b,        // [d] fp32
    const int*   __restrict__ anchor,   // [A] int32
    float* __restrict__ P,              // [A, d]   (ws)
    float* __restrict__ T2b)            // [625, d] (ws)
{
    __shared__ float W_s[128 * 4 * WP4];    // 128 rows x 132 floats = 66 KB
    __shared__ float X_s[PPB * LATDIM];     // inputs to phase-2 (4 KB)
    __shared__ float R_s[PPB * LATDIM];     // cross-half partials (4 KB)
    const int tid = threadIdx.x;            // 0..255
    const bool isP = (blockIdx.x < PBLK);
    const int off = isP ? 0 : LATDIM;       // which W half
    float4* W_s4 = (float4*)W_s;
    const float4* X_s4 = (const float4*)X_s;
    const int col = tid & 127;              // output channel / column
    const int h   = tid >> 7;               // k-half / row-half: 0 or 1

    // Stage W-half into LDS: W_s[r*132+c] = W[r*256+off+c]. Global float4
    // coalesced; pad 33 float4s/row -> phase-2 b128 reads are at the
    // 8-access/bank floor (measured 0 SQ_LDS_BANK_CONFLICT in r4).
    #pragma unroll
    for (int it = 0; it < 16; ++it) {
        int f = it * 256 + tid;          // 0..4095
        int r = f >> 5, c4 = f & 31;
        W_s4[r * WP4 + c4] =
            *(const float4*)(W + r * (2 * LATDIM) + off + 4 * c4);
    }

    if (isP) {
        const int a0 = blockIdx.x * PPB;
        // Anchor rows -> X_s (j uniform per wave -> scalar anchor load).
        #pragma unroll
        for (int it = 0; it < 4; ++it) {
            int idx = it * 256 + tid;        // 0..1023
            int j = idx >> 7, c = idx & 127;
            X_s[j * LATDIM + c] = embeds[(size_t)anchor[a0 + j] * LATDIM + c];
        }
        __syncthreads();   // covers W_s too

        // Phase 2, split-k: half h covers k4 in [16h, 16h+16).
        float acc[PPB] = {};
        #pragma unroll
        for (int k4 = 0; k4 < 16; ++k4) {
            int kk = h * 16 + k4;
            float4 w = W_s4[col * WP4 + kk];
            #pragma unroll
            for (int j = 0; j < PPB; ++j) {
                float4 e = X_s4[j * 32 + kk];   // broadcast
                acc[j] += e.x*w.x + e.y*w.y + e.z*w.z + e.w*w.w;
            }
        }
        if (h == 1) {
            #pragma unroll
            for (int j = 0; j < PPB; ++j) R_s[j * LATDIM + col] = acc[j];
        }
        __syncthreads();
        if (h == 0) {
            #pragma unroll
            for (int j = 0; j < PPB; ++j)
                P[(size_t)(a0 + j) * LATDIM + col] =
                    acc[j] + R_s[j * LATDIM + col];
        }
    } else {
        const int s0 = (blockIdx.x - PBLK) * SPB;
        // Phase 1: 4 disjoint 64-row windows; half h takes rows r≡h (mod 2).
        float acc[SPB] = {};
        #pragma unroll
        for (int j = 0; j < SPB; ++j) {
            int base = ((s0 + j) * ANUM) % NNODES;
            #pragma unroll 8
            for (int r = h; r < ANUM; r += 2) {
                int row = base + r;
                if (row >= NNODES) row -= NNODES;
                acc[j] += embeds[(size_t)row * LATDIM + col];
            }
        }
        if (h == 1) {
            #pragma unroll
            for (int j = 0; j < SPB; ++j) R_s[j * LATDIM + col] = acc[j];
        }
        __syncthreads();   // covers W_s too
        if (h == 0) {
            #pragma unroll
            for (int j = 0; j < SPB; ++j)
                X_s[j * LATDIM + col] = acc[j] + R_s[j * LATDIM + col];
        }
        __syncthreads();

        // Phase 2, split-k.
        float acc2[SPB] = {};
        #pragma unroll
        for (int k4 = 0; k4 < 16; ++k4) {
            int kk = h * 16 + k4;
            float4 w = W_s4[col * WP4 + kk];
            #pragma unroll
            for (int j = 0; j < SPB; ++j) {
                float4 s = X_s4[j * 32 + kk];   // broadcast
                acc2[j] += s.x*w.x + s.y*w.y + s.z*w.z + s.w*w.w;
            }
        }
        if (h == 1) {
            #pragma unroll
            for (int j = 0; j < SPB; ++j) R_s[j * LATDIM + col] = acc2[j];
        }
        __syncthreads();
        if (h == 0) {
            const float bias = b[col];
            #pragma unroll
            for (int j = 0; j < SPB; ++j) {
                int s = s0 + j;
                if (s < PERIOD)
                    T2b[(size_t)s * LATDIM + col] =
                        bias + (acc2[j] + R_s[j * LATDIM + col]) * (1.0f / ANUM);
            }
        }
    }
}

// out[n,o] = (1/A) * sum_a dists[a,n] * P[a,o] + T2b[n%625, o]
// (byte-identical to r4's measured-good main kernel)
__global__ __launch_bounds__(256) void main_kernel(
    const float* __restrict__ dists,    // [A, N] fp32
    const float* __restrict__ P,        // [A, d]
    const float* __restrict__ T2b,      // [625, d]
    float* __restrict__ out)            // [N, d] fp32
{
    __shared__ float P_s[ANUM * LATDIM];   // 32 KB
    const int tid = threadIdx.x;

    {   // stage P, coalesced float4
        float4* P_s4 = (float4*)P_s;
        const float4* Pg = (const float4*)P;
        #pragma unroll
        for (int it = 0; it < (ANUM * LATDIM / 4) / 256; ++it)
            P_s4[it * 256 + tid] = Pg[it * 256 + tid];
    }
    __syncthreads();

    const int lane = tid & 63;
    const int w    = __builtin_amdgcn_readfirstlane(tid >> 6);  // uniform 0..3
    const int o    = (w & 1) * 64 + lane;   // output channel
    const int nc   = w >> 1;                // n-chunk within block
    int nb = blockIdx.x * TN + nc * 16;     // uniform chunk base
    const bool live = (nb + 16) <= NNODES;  // chunks 16-aligned; N%16==0
    if (!live) nb = NNODES - 16;            // clamp loads; stores guarded

    float acc[16] = {};
    for (int a = 0; a < ANUM; ++a) {
        const float p = P_s[a * LATDIM + o];                 // per-lane LDS
        const float* __restrict__ drow = dists + (size_t)a * NNODES + nb;
        #pragma unroll
        for (int j = 0; j < 16; ++j)
            acc[j] += drow[j] * p;                           // uniform loads
    }

    if (live) {
        #pragma unroll
        for (int j = 0; j < 16; ++j) {
            const int n = nb + j;
            const int s = n % PERIOD;
            out[(size_t)n * LATDIM + o] =
                acc[j] * (1.0f / ANUM) + T2b[(size_t)s * LATDIM + o];
        }
    }
}

extern "C" void kernel_launch(void* const* d_in, const int* in_sizes, int n_in,
                              void* d_out, int out_size, void* d_ws, size_t ws_size,
                              hipStream_t stream) {
    const float* embeds = (const float*)d_in[0];   // [10000,128] fp32
    const float* dists  = (const float*)d_in[1];   // [64,10000]  fp32
    const float* W      = (const float*)d_in[2];   // [128,256]   fp32
    const float* b      = (const float*)d_in[3];   // [128]       fp32
    const int*   anchor = (const int*)d_in[4];     // [64]        int32
    float* out = (float*)d_out;                    // [10000,128] fp32

    float* P   = (float*)d_ws;            // 64*128 floats   = 32 KB
    float* T2b = P + ANUM * LATDIM;       // 625*128 floats  = 320 KB

    prep_kernel<<<PBLK + TBLK, 256, 0, stream>>>(embeds, W, b, anchor, P, T2b);
    main_kernel<<<(NNODES + TN - 1) / TN, 256, 0, stream>>>(dists, P, T2b, out);
}

// Round 7
// 79.895 us; speedup vs baseline: 3.8281x; 1.0496x over previous
//
#include <hip/hip_runtime.h>

// Problem constants (from reference setup_inputs)
#define LATDIM 128     // d
#define ANUM   64      // anchor sets A
#define NNODES 10000   // N
#define PERIOD 625     // period of (64*i mod 10000); gcd(64,10000)=16
#define TN     32      // n per main block
#define PPB    8       // anchors per P-block
#define PBLK   (ANUM / PPB)   // 8 P-blocks
#define TBLK   157            // T2-blocks; block t owns s in {t, t+157k}, k<4
#define WP4    33      // W_s row stride in float4 units (132 floats)

// ---------------------------------------------------------------------------
// Verified algebra (r3/r4/r6 passed, absmax 9.8e-4):
//   out[n,o] = (1/A)*sum_a dists[a,n]*P[a,o] + T2b[n%625,o]
//   P[a,o]   = sum_k E[anchor[a],k]*W[o,k]
//   T2b[s,o] = b[o] + (1/A)*sum_k S[s,k]*W[o,128+k], S[s,k]=sum_a E[(64s+a)%N,k]
//
// r7 delta: T-phase window REGROUPING. 64*157 == 48 (mod 10000), so windows
// {t, t+157, t+314, t+471} span one contiguous 208-row range [64t, 64t+208):
//   w0:[0,64) w1:[48,112) w2:[96,160) w3:[144,208)  (offsets within span)
// -> 208 row-loads feed 4 windows (was 256), static segment masks, spans of
// adjacent blocks overlap 144 rows (L2-friendly). s=t+157k unique, k=s/157.
// Main kernel: byte-identical to r4/r6 measured-good version.
// r5 lesson kept: no cross-block flags, no p[64] VGPR arrays.
// ---------------------------------------------------------------------------

__global__ __launch_bounds__(256) void prep_kernel(
    const float* __restrict__ embeds,   // [N, d] fp32
    const float* __restrict__ W,        // [d, 2d] fp32 row-major
    const float* __restrict__ b,        // [d] fp32
    const int*   __restrict__ anchor,   // [A] int32
    float* __restrict__ P,              // [A, d]   (ws)
    float* __restrict__ T2b)            // [625, d] (ws)
{
    __shared__ float W_s[128 * 4 * WP4];    // 128 rows x 132 floats = 66 KB
    __shared__ float X_s[PPB * LATDIM];     // phase-2 inputs (4 KB)
    __shared__ float R_s[PPB * LATDIM];     // cross-half partials (4 KB)
    const int tid = threadIdx.x;            // 0..255
    const bool isP = (blockIdx.x < PBLK);
    const int off = isP ? 0 : LATDIM;       // which W half
    float4* W_s4 = (float4*)W_s;
    const float4* X_s4 = (const float4*)X_s;
    const int col = tid & 127;              // output channel / column
    const int h   = tid >> 7;               // half: 0 or 1

    // Stage W-half into LDS (coalesced float4; pad-33 rows: 0 conflicts
    // measured r4/r6).
    #pragma unroll
    for (int it = 0; it < 16; ++it) {
        int f = it * 256 + tid;          // 0..4095
        int r = f >> 5, c4 = f & 31;
        W_s4[r * WP4 + c4] =
            *(const float4*)(W + r * (2 * LATDIM) + off + 4 * c4);
    }

    if (isP) {
        const int a0 = blockIdx.x * PPB;
        #pragma unroll
        for (int it = 0; it < 4; ++it) {
            int idx = it * 256 + tid;        // 0..1023
            int j = idx >> 7, c = idx & 127;
            X_s[j * LATDIM + c] = embeds[(size_t)anchor[a0 + j] * LATDIM + c];
        }
        __syncthreads();   // covers W_s too

        // Phase 2, split-k across halves.
        float acc[PPB] = {};
        #pragma unroll
        for (int k4 = 0; k4 < 16; ++k4) {
            int kk = h * 16 + k4;
            float4 w = W_s4[col * WP4 + kk];
            #pragma unroll
            for (int j = 0; j < PPB; ++j) {
                float4 e = X_s4[j * 32 + kk];   // broadcast
                acc[j] += e.x*w.x + e.y*w.y + e.z*w.z + e.w*w.w;
            }
        }
        if (h == 1) {
            #pragma unroll
            for (int j = 0; j < PPB; ++j) R_s[j * LATDIM + col] = acc[j];
        }
        __syncthreads();
        if (h == 0) {
            #pragma unroll
            for (int j = 0; j < PPB; ++j)
                P[(size_t)(a0 + j) * LATDIM + col] =
                    acc[j] + R_s[j * LATDIM + col];
        }
    } else {
        const int t = blockIdx.x - PBLK;     // 0..156
        const int rbase = 64 * t;            // span start (<= 9984)
        // Phase 1: one sweep over 208 contiguous rows; segment masks route
        // each row into the window(s) containing it. Half h takes r = h mod 2.
        float acc[4] = {};
        #define LDROW(r_) ({ int row_ = rbase + (r_);                        \
                             if (row_ >= NNODES) row_ -= NNODES;             \
                             embeds[(size_t)row_ * LATDIM + col]; })
        #pragma unroll
        for (int i = 0; i < 24; ++i) {                 // [0,48) -> w0
            acc[0] += LDROW(h + 2 * i);
        }
        #pragma unroll
        for (int i = 0; i < 8; ++i) {                  // [48,64) -> w0,w1
            float v = LDROW(48 + h + 2 * i); acc[0] += v; acc[1] += v;
        }
        #pragma unroll
        for (int i = 0; i < 16; ++i) {                 // [64,96) -> w1
            acc[1] += LDROW(64 + h + 2 * i);
        }
        #pragma unroll
        for (int i = 0; i < 8; ++i) {                  // [96,112) -> w1,w2
            float v = LDROW(96 + h + 2 * i); acc[1] += v; acc[2] += v;
        }
        #pragma unroll
        for (int i = 0; i < 16; ++i) {                 // [112,144) -> w2
            acc[2] += LDROW(112 + h + 2 * i);
        }
        #pragma unroll
        for (int i = 0; i < 8; ++i) {                  // [144,160) -> w2,w3
            float v = LDROW(144 + h + 2 * i); acc[2] += v; acc[3] += v;
        }
        #pragma unroll
        for (int i = 0; i < 24; ++i) {                 // [160,208) -> w3
            acc[3] += LDROW(160 + h + 2 * i);
        }
        #undef LDROW

        if (h == 1) {
            #pragma unroll
            for (int j = 0; j < 4; ++j) R_s[j * LATDIM + col] = acc[j];
        }
        __syncthreads();   // covers W_s too
        if (h == 0) {
            #pragma unroll
            for (int j = 0; j < 4; ++j)
                X_s[j * LATDIM + col] = acc[j] + R_s[j * LATDIM + col];
        }
        __syncthreads();

        // Phase 2, split-k across halves.
        float acc2[4] = {};
        #pragma unroll
        for (int k4 = 0; k4 < 16; ++k4) {
            int kk = h * 16 + k4;
            float4 w = W_s4[col * WP4 + kk];
            #pragma unroll
            for (int j = 0; j < 4; ++j) {
                float4 s = X_s4[j * 32 + kk];   // broadcast
                acc2[j] += s.x*w.x + s.y*w.y + s.z*w.z + s.w*w.w;
            }
        }
        if (h == 1) {
            #pragma unroll
            for (int j = 0; j < 4; ++j) R_s[j * LATDIM + col] = acc2[j];
        }
        __syncthreads();
        if (h == 0) {
            const float bias = b[col];
            #pragma unroll
            for (int j = 0; j < 4; ++j) {
                int s = t + 157 * j;            // unique s per (t,j)
                if (s < PERIOD)
                    T2b[(size_t)s * LATDIM + col] =
                        bias + (acc2[j] + R_s[j * LATDIM + col]) * (1.0f / ANUM);
            }
        }
    }
}

// out[n,o] = (1/A) * sum_a dists[a,n] * P[a,o] + T2b[n%625, o]
// (byte-identical to r4/r6's measured-good main kernel)
__global__ __launch_bounds__(256) void main_kernel(
    const float* __restrict__ dists,    // [A, N] fp32
    const float* __restrict__ P,        // [A, d]
    const float* __restrict__ T2b,      // [625, d]
    float* __restrict__ out)            // [N, d] fp32
{
    __shared__ float P_s[ANUM * LATDIM];   // 32 KB
    const int tid = threadIdx.x;

    {   // stage P, coalesced float4
        float4* P_s4 = (float4*)P_s;
        const float4* Pg = (const float4*)P;
        #pragma unroll
        for (int it = 0; it < (ANUM * LATDIM / 4) / 256; ++it)
            P_s4[it * 256 + tid] = Pg[it * 256 + tid];
    }
    __syncthreads();

    const int lane = tid & 63;
    const int w    = __builtin_amdgcn_readfirstlane(tid >> 6);  // uniform 0..3
    const int o    = (w & 1) * 64 + lane;   // output channel
    const int nc   = w >> 1;                // n-chunk within block
    int nb = blockIdx.x * TN + nc * 16;     // uniform chunk base
    const bool live = (nb + 16) <= NNODES;  // chunks 16-aligned; N%16==0
    if (!live) nb = NNODES - 16;            // clamp loads; stores guarded

    float acc[16] = {};
    for (int a = 0; a < ANUM; ++a) {
        const float p = P_s[a * LATDIM + o];                 // per-lane LDS
        const float* __restrict__ drow = dists + (size_t)a * NNODES + nb;
        #pragma unroll
        for (int j = 0; j < 16; ++j)
            acc[j] += drow[j] * p;                           // uniform loads
    }

    if (live) {
        #pragma unroll
        for (int j = 0; j < 16; ++j) {
            const int n = nb + j;
            const int s = n % PERIOD;
            out[(size_t)n * LATDIM + o] =
                acc[j] * (1.0f / ANUM) + T2b[(size_t)s * LATDIM + o];
        }
    }
}

extern "C" void kernel_launch(void* const* d_in, const int* in_sizes, int n_in,
                              void* d_out, int out_size, void* d_ws, size_t ws_size,
                              hipStream_t stream) {
    const float* embeds = (const float*)d_in[0];   // [10000,128] fp32
    const float* dists  = (const float*)d_in[1];   // [64,10000]  fp32
    const float* W      = (const float*)d_in[2];   // [128,256]   fp32
    const float* b      = (const float*)d_in[3];   // [128]       fp32
    const int*   anchor = (const int*)d_in[4];     // [64]        int32
    float* out = (float*)d_out;                    // [10000,128] fp32

    float* P   = (float*)d_ws;            // 64*128 floats   = 32 KB
    float* T2b = P + ANUM * LATDIM;       // 625*128 floats  = 320 KB

    prep_kernel<<<PBLK + TBLK, 256, 0, stream>>>(embeds, W, b, anchor, P, T2b);
    main_kernel<<<(NNODES + TN - 1) / TN, 256, 0, stream>>>(dists, P, T2b, out);
}